// Round 5
// baseline (245.147 us; speedup 1.0000x reference)
//
#include <hip/hip_runtime.h>
#include <math.h>

// Problem constants
#define GNUM 64
#define DDIM 64
#define EDIM 32
#define UNK_CLASS 80
#define DBLK 2048                 // density blocks: 4 threads per pixel (131072*4/256)
#define ABLK 4096                 // AE blocks: 32KB contiguous per block
#define NBLK (DBLK + ABLK)        // 6144

// Density work is split 4-ways per pixel (lane group {4p..4p+3}):
//   - IoU argmax: lane q scans boxes [16q,16q+16), then 2-step butterfly merge
//     with exact first-max tie-break (equal iou -> min g).
//   - MLP: lane q computes all 64 d for its 8 of 32 e-columns (h recomputed
//     from xv, 2 ops) -> no acc reduction; final p via 2 shuffle-adds.
// This fixes rounds 1-4's real limiter: a 512-block density tail at 2
// waves/SIMD (r1: OccupancyPercent=25%) that was latency-bound regardless of
// inner-loop form. Now density = 2048 short blocks, interleaved b%3 with the
// 4096 AE streaming blocks so VALU work hides under HBM traffic.
__global__ __launch_bounds__(256) void fused_kernel(
    const float* __restrict__ err,        // [N,256,128,128]
    const float* __restrict__ err_map,    // [N,1,128,128]
    const float* __restrict__ gt_boxes,   // [N,64,4]
    const float* __restrict__ w1,         // [1,64]
    const float* __restrict__ b1,         // [64]
    const float* __restrict__ w2,         // [64,32] row-major
    const float* __restrict__ b2,         // [32]
    const float* __restrict__ w3,         // [32,1]
    const float* __restrict__ b3,         // [1]
    const int*   __restrict__ gt_classes, // [N,64]
    float* __restrict__ ws)               // [DBLK] density + [ABLK] AE partials
{
    const int t = threadIdx.x;
    const int b = blockIdx.x;
    float part = 0.0f;          // density blocks: BCE partial; AE blocks: sumsq partial
    int wsIdx;
    __shared__ float red[4];

    if (b % 3 != 0) {
        // ---------------- AE sum-of-squares: 8 loads in flight, 32KB/block ----
        const int ab = b - b/3 - 1;                       // [0,4096)
        wsIdx = DBLK + ab;
        const float4* __restrict__ e4 = (const float4*)err;
        const int base = ab * 2048 + t;                   // block-contiguous chunk
        float4 v0 = e4[base + 0*256];
        float4 v1 = e4[base + 1*256];
        float4 v2 = e4[base + 2*256];
        float4 v3 = e4[base + 3*256];
        float4 v4 = e4[base + 4*256];
        float4 v5 = e4[base + 5*256];
        float4 v6 = e4[base + 6*256];
        float4 v7 = e4[base + 7*256];
        float s0, s1, s2, s3;
        s0 = v0.x*v0.x; s1 = v0.y*v0.y; s2 = v0.z*v0.z; s3 = v0.w*v0.w;
        s0 = fmaf(v1.x,v1.x,s0); s1 = fmaf(v1.y,v1.y,s1); s2 = fmaf(v1.z,v1.z,s2); s3 = fmaf(v1.w,v1.w,s3);
        s0 = fmaf(v2.x,v2.x,s0); s1 = fmaf(v2.y,v2.y,s1); s2 = fmaf(v2.z,v2.z,s2); s3 = fmaf(v2.w,v2.w,s3);
        s0 = fmaf(v3.x,v3.x,s0); s1 = fmaf(v3.y,v3.y,s1); s2 = fmaf(v3.z,v3.z,s2); s3 = fmaf(v3.w,v3.w,s3);
        s0 = fmaf(v4.x,v4.x,s0); s1 = fmaf(v4.y,v4.y,s1); s2 = fmaf(v4.z,v4.z,s2); s3 = fmaf(v4.w,v4.w,s3);
        s0 = fmaf(v5.x,v5.x,s0); s1 = fmaf(v5.y,v5.y,s1); s2 = fmaf(v5.z,v5.z,s2); s3 = fmaf(v5.w,v5.w,s3);
        s0 = fmaf(v6.x,v6.x,s0); s1 = fmaf(v6.y,v6.y,s1); s2 = fmaf(v6.z,v6.z,s2); s3 = fmaf(v6.w,v6.w,s3);
        s0 = fmaf(v7.x,v7.x,s0); s1 = fmaf(v7.y,v7.y,s1); s2 = fmaf(v7.z,v7.z,s2); s3 = fmaf(v7.w,v7.w,s3);
        part = (s0+s1) + (s2+s3);
    } else {
        // ---------------- density: 4 threads per pixel ----------------
        const int db   = b / 3;                 // [0,2048)
        wsIdx = db;
        const int dtid = (db << 8) | t;
        const int pix  = dtid >> 2;             // [0,131072)
        const int q    = dtid & 3;              // lane role within pixel group
        const int n    = pix >> 14;             // image (uniform per block)
        const int m    = pix & 16383;           // pixel in image

        // ---- anchors at this pixel (A=3 aspect ratios, detectron2 order) ----
        const float cx = (float)(m & 127) * 8.0f;
        const float cy = (float)(m >> 7) * 8.0f;
        const float s05 = sqrtf(0.5f), s2r = sqrtf(2.0f);
        const float hw0 = 0.5f*(32.0f/s05), hh0 = 0.5f*(32.0f*s05);
        const float hw1 = 16.0f,            hh1 = 16.0f;
        const float hw2 = 0.5f*(32.0f/s2r), hh2 = 0.5f*(32.0f*s2r);

        const float ax1[3] = {cx-hw0, cx-hw1, cx-hw2};
        const float ay1[3] = {cy-hh0, cy-hh1, cy-hh2};
        const float ax2[3] = {cx+hw0, cx+hw1, cx+hw2};
        const float ay2[3] = {cy+hh0, cy+hh1, cy+hh2};
        float areaA[3];
        #pragma unroll
        for (int a = 0; a < 3; ++a) areaA[a] = (ax2[a]-ax1[a])*(ay2[a]-ay1[a]);

        // ---- per-lane argmax over boxes [16q, 16q+16) ----
        // iou kept as (inter, dn); sentinel (-1,1) always loses to any real box
        float bi[3] = {-1.f,-1.f,-1.f}, bd[3] = {1.f,1.f,1.f};
        int   idx[3] = {0,0,0};

        const float4* __restrict__ bp = (const float4*)(gt_boxes + n*GNUM*4);
        #pragma unroll 4
        for (int i = 0; i < 16; ++i) {
            const int g = (q << 4) | i;
            const float4 bx = bp[g];                     // per-lane VMEM, L1/L2-hit
            const float areaB = (bx.z-bx.x)*(bx.w-bx.y);
            #pragma unroll
            for (int a = 0; a < 3; ++a) {
                float lx = fmaxf(bx.x, ax1[a]), ly = fmaxf(bx.y, ay1[a]);
                float rx = fminf(bx.z, ax2[a]), ry = fminf(bx.w, ay2[a]);
                float iw = fmaxf(rx-lx, 0.f),   ih = fmaxf(ry-ly, 0.f);
                float inter = iw*ih;
                float dn = fmaxf(areaB + areaA[a] - inter, 1e-9f);
                // strict > keeps FIRST max within this lane's range
                if (inter*bd[a] > bi[a]*dn) { bi[a]=inter; bd[a]=dn; idx[a]=g; }
            }
        }
        // ---- butterfly merge over the 4-lane group (xor 1, then 2) ----
        #pragma unroll
        for (int mask = 1; mask <= 2; mask <<= 1) {
            #pragma unroll
            for (int a = 0; a < 3; ++a) {
                float ri = __shfl_xor(bi[a], mask, 64);
                float rd = __shfl_xor(bd[a], mask, 64);
                int   rx = __shfl_xor(idx[a], mask, 64);
                float lhs = ri*bd[a], rhs = bi[a]*rd;
                // strictly greater, or equal with lower g (first-max semantics)
                bool take = (lhs > rhs) || ((lhs == rhs) && (rx < idx[a]));
                if (take) { bi[a]=ri; bd[a]=rd; idx[a]=rx; }
            }
        }
        const int* __restrict__ cp = gt_classes + n*GNUM;
        const bool unk = (cp[idx[0]] == UNK_CLASS) |
                         (cp[idx[1]] == UNK_CLASS) |
                         (cp[idx[2]] == UNK_CLASS);
        const float mask01 = unk ? 1.0f : 0.0f;

        // ---- MLP: lane q owns e-columns [8q, 8q+8); h recomputed per d ----
        const float xv = err_map[pix];
        float acc[8] = {0,0,0,0,0,0,0,0};
        const float4* __restrict__ w2v = (const float4*)(w2 + (q << 3));
        #pragma unroll 4
        for (int d = 0; d < DDIM; ++d) {
            const float h = fmaxf(fmaf(xv, w1[d], b1[d]), 0.0f);  // w1/b1: s_load
            const float4 wa = w2v[d*8 + 0];                        // w2 row d, my cols
            const float4 wb = w2v[d*8 + 1];
            acc[0] = fmaf(h, wa.x, acc[0]); acc[1] = fmaf(h, wa.y, acc[1]);
            acc[2] = fmaf(h, wa.z, acc[2]); acc[3] = fmaf(h, wa.w, acc[3]);
            acc[4] = fmaf(h, wb.x, acc[4]); acc[5] = fmaf(h, wb.y, acc[5]);
            acc[6] = fmaf(h, wb.z, acc[6]); acc[7] = fmaf(h, wb.w, acc[7]);
        }
        float pq = 0.0f;
        #pragma unroll
        for (int j = 0; j < 8; ++j) {
            const int e = (q << 3) + j;
            pq = fmaf(fmaxf(acc[j] + b2[e], 0.0f), w3[e], pq);
        }
        // sum partial dot over the 4 lanes
        pq += __shfl_xor(pq, 1, 64);
        pq += __shfl_xor(pq, 2, 64);
        const float p = pq + b3[0];

        // stable BCE-with-logits term; count each pixel once (lane q==0)
        if (q == 0)
            part = fmaxf(p, 0.0f) + log1pf(expf(-fabsf(p))) - p*mask01;
    }

    // ---- block reduction -> ws[wsIdx] ----
    float x = part;
    #pragma unroll
    for (int off = 32; off > 0; off >>= 1) x += __shfl_xor(x, off, 64);
    if ((t & 63) == 0) red[t >> 6] = x;
    __syncthreads();
    if (t == 0) ws[wsIdx] = (red[0]+red[1]) + (red[2]+red[3]);
}

__global__ __launch_bounds__(256) void finalize_kernel(const float* __restrict__ ws,
                                                       float* __restrict__ out)
{
    const int t = threadIdx.x;
    float sd = 0.f, sa = 0.f;
    for (int i = t; i < DBLK; i += 256) sd += ws[i];
    for (int i = DBLK + t; i < NBLK; i += 256) sa += ws[i];
    #pragma unroll
    for (int off = 32; off > 0; off >>= 1) {
        sd += __shfl_xor(sd, off, 64);
        sa += __shfl_xor(sa, off, 64);
    }
    __shared__ float rd[4], ra[4];
    if ((t & 63) == 0) { rd[t >> 6] = sd; ra[t >> 6] = sa; }
    __syncthreads();
    if (t == 0) {
        out[0] = ((ra[0]+ra[1])+(ra[2]+ra[3])) * (1.0f/33554432.0f); // loss_ae
        out[1] = ((rd[0]+rd[1])+(rd[2]+rd[3])) * (1.0f/131072.0f);   // loss_density
    }
}

extern "C" void kernel_launch(void* const* d_in, const int* in_sizes, int n_in,
                              void* d_out, int out_size, void* d_ws, size_t ws_size,
                              hipStream_t stream) {
    const float* err        = (const float*)d_in[0];
    const float* err_map    = (const float*)d_in[1];
    const float* gt_boxes   = (const float*)d_in[2];
    const float* w1         = (const float*)d_in[3];
    const float* b1         = (const float*)d_in[4];
    const float* w2         = (const float*)d_in[5];
    const float* b2         = (const float*)d_in[6];
    const float* w3         = (const float*)d_in[7];
    const float* b3         = (const float*)d_in[8];
    const int*   gt_classes = (const int*)d_in[9];
    float* out = (float*)d_out;
    float* ws  = (float*)d_ws;

    fused_kernel<<<NBLK, 256, 0, stream>>>(err, err_map, gt_boxes, w1, b1, w2, b2,
                                           w3, b3, gt_classes, ws);
    finalize_kernel<<<1, 256, 0, stream>>>(ws, out);
}